// Round 12
// baseline (354.457 us; speedup 1.0000x reference)
//
#include <hip/hip_runtime.h>
#include <hip/hip_bf16.h>

// Problem constants
#define BB 128
#define TT 512
#define DD 128
#define CAP 64            // per-column nonzero list capacity (overflow -> dense fallback)
#define NMAT 2048         // matmul blocks
#define NRMP 256          // ramp blocks: B*T/256 = 65536/256 (R11 bug: was 128)

// Native vector type (clean dwordx4 codegen).
typedef float f4 __attribute__((ext_vector_type(4)));

// Output layout (flat float32, concatenated in reference return order)
static const size_t OFF_S2B  = 0;                       // SeqtoBlur  [B,T,T]
static const size_t OFF_AVG  = (size_t)BB * TT * TT;    // avged_seq  [B,T,D]
static const size_t OFF_R    = OFF_AVG + (size_t)BB * TT * DD;  // R [B,T]
static const size_t OFF_AR   = OFF_R + (size_t)BB * TT;         // avged_R [B,T]
static const size_t OFF_LEN  = OFF_AR + (size_t)BB * TT;        // avged_len [B]

// ---------------------------------------------------------------------------
// Matmul + ramps kernel (grid = NMAT + NRMP). The 268 MB SeqtoBlur
// passthrough is offloaded to hipMemcpyAsync (runtime-tuned copy — the same
// kernel family as the harness fill that sustains 6.6 TB/s, vs the ~2.5 TB/s
// every hand-written variant of mine has capped at across R7-R10).
//
// Matmul sparsity structure (verified against every reference branch):
//   * Tc = len_seq[b] <= 2 -> BlurMat == I -> avged_seq[b] = seq[b]
//   * all nonzeros have col < avged_len[b] -> chunks beyond: write zeros
//   * nonzeros in column i have row in [i, Tc) -> read row-groups [i0, Tc)
// ---------------------------------------------------------------------------
__global__ __launch_bounds__(256) void blur_matmul_ramps(
        const float* __restrict__ seq,        // [B,T,D]
        const int*   __restrict__ len_seq,    // [B]
        const float* __restrict__ BlurMat,    // [B,T,T]
        const int*   __restrict__ avged_len,  // [B]
        float* __restrict__ out) {

    __shared__ int   cnt[32];
    __shared__ int   tlist[32][CAP];
    __shared__ float wlist[32][CAP];

    int blk = blockIdx.x;
    int tid = threadIdx.x;

    if (blk >= NMAT) {
        // ===== Role C: ramps + avged_len cast =====
        int idx = (blk - NMAT) * 256 + tid;   // [0, B*T)
        int b = idx >> 9;          // /T
        int t = idx & (TT - 1);
        float l1 = (float)len_seq[b];
        float l2 = (float)avged_len[b];
        float p = (float)t;
        out[OFF_R  + idx] = (p < l1) ? (p + 1.f) / fmaxf(l1, 1.f) : 0.f;
        out[OFF_AR + idx] = (p < l2) ? (p + 1.f) / fmaxf(l2, 1.f) : 0.f;
        if (t == 0) out[OFF_LEN + b] = l2;
        return;
    }

    // ===== Role A: avged_seq[b,i,d] = sum_t BlurMat[b,t,i]*seq[b,t,d] =====
    int q  = blk;
    int b  = q >> 4;             // 16 column-chunks per batch
    int i0 = (q & 15) * 32;
    int Tc = len_seq[b];
    int navl = avged_len[b];

    int il = tid & 31;           // owned column within chunk
    int dbase = (tid >> 5) * 16; // owned d-range

    if (Tc <= 2) {
        // BlurMat == I_512: avged_seq[b] = seq[b]. Pure 16B-per-lane copy.
        const f4* srow = (const f4*)(seq + ((size_t)b * TT + i0 + il) * DD + dbase);
        f4* drow = (f4*)(out + OFF_AVG + ((size_t)b * TT + i0 + il) * DD + dbase);
        #pragma unroll
        for (int k = 0; k < 4; ++k) drow[k] = srow[k];
        return;   // block-uniform exit
    }

    if (i0 >= navl) {
        // Column-cut: every column in this chunk is all-zero -> write zeros.
        f4 z = {0.f, 0.f, 0.f, 0.f};
        f4* drow = (f4*)(out + OFF_AVG + ((size_t)b * TT + i0 + il) * DD + dbase);
        #pragma unroll
        for (int k = 0; k < 4; ++k) drow[k] = z;
        return;   // block-uniform exit (navl is uniform across the block)
    }

    if (tid < 32) cnt[tid] = 0;
    __syncthreads();

    const float* Ab = BlurMat + (size_t)b * TT * TT;
    int ci = (tid & 7) * 4;
    int t0 = tid >> 3;                 // 0..31
    int g0   = i0 >> 7;                // first row-group that can hold a nonzero
    int gend = (Tc + 127) >> 7;        // 1..4, block-uniform

    // Phase 1a: issue all loads before any compaction (deep MLP).
    f4 v[16];
    #pragma unroll
    for (int g = 0; g < 4; ++g) {
        if (g >= g0 && g < gend) {
            #pragma unroll
            for (int qq = 0; qq < 4; ++qq) {
                int t = t0 + g * 128 + qq * 32;
                v[g * 4 + qq] = *(const f4*)(Ab + (size_t)t * TT + i0 + ci);
            }
        }
    }

    // Phase 1b: compact nonzeros into per-column LDS lists.
    #pragma unroll
    for (int g = 0; g < 4; ++g) {
        if (g >= g0 && g < gend) {
            #pragma unroll
            for (int qq = 0; qq < 4; ++qq) {
                int t = t0 + g * 128 + qq * 32;
                f4 w4 = v[g * 4 + qq];
                if (w4.x != 0.f) { int s = atomicAdd(&cnt[ci+0], 1); if (s < CAP) { tlist[ci+0][s] = t; wlist[ci+0][s] = w4.x; } }
                if (w4.y != 0.f) { int s = atomicAdd(&cnt[ci+1], 1); if (s < CAP) { tlist[ci+1][s] = t; wlist[ci+1][s] = w4.y; } }
                if (w4.z != 0.f) { int s = atomicAdd(&cnt[ci+2], 1); if (s < CAP) { tlist[ci+2][s] = t; wlist[ci+2][s] = w4.z; } }
                if (w4.w != 0.f) { int s = atomicAdd(&cnt[ci+3], 1); if (s < CAP) { tlist[ci+3][s] = t; wlist[ci+3][s] = w4.w; } }
            }
        }
    }
    __syncthreads();

    // Phase 2: apply the (few) nonzeros of the owned column.
    float acc[16];
    #pragma unroll
    for (int k = 0; k < 16; ++k) acc[k] = 0.f;

    const float* Sb = seq + (size_t)b * TT * DD + dbase;
    int n = cnt[il];

    if (n <= CAP) {
        for (int j = 0; j < n; ++j) {
            int   t = tlist[il][j];
            float w = wlist[il][j];
            const float* srow = Sb + (size_t)t * DD;
            #pragma unroll
            for (int k = 0; k < 4; ++k) {
                float4 s = *(const float4*)(srow + k * 4);
                acc[k*4+0] += w * s.x;
                acc[k*4+1] += w * s.y;
                acc[k*4+2] += w * s.z;
                acc[k*4+3] += w * s.w;
            }
        }
    } else {
        // Dense fallback (list overflow) — data-dependent safety net.
        for (int t = i0; t < Tc; ++t) {
            float w = Ab[(size_t)t * TT + i0 + il];
            if (w != 0.f) {
                const float* srow = Sb + (size_t)t * DD;
                #pragma unroll
                for (int k = 0; k < 4; ++k) {
                    float4 s = *(const float4*)(srow + k * 4);
                    acc[k*4+0] += w * s.x;
                    acc[k*4+1] += w * s.y;
                    acc[k*4+2] += w * s.z;
                    acc[k*4+3] += w * s.w;
                }
            }
        }
    }

    float* Cb = out + OFF_AVG + (size_t)b * TT * DD + (size_t)(i0 + il) * DD + dbase;
    #pragma unroll
    for (int k = 0; k < 4; ++k) {
        *(float4*)(Cb + k * 4) = make_float4(acc[k*4], acc[k*4+1], acc[k*4+2], acc[k*4+3]);
    }
}

extern "C" void kernel_launch(void* const* d_in, const int* in_sizes, int n_in,
                              void* d_out, int out_size, void* d_ws, size_t ws_size,
                              hipStream_t stream) {
    const float* seq       = (const float*)d_in[0];
    const int*   len_seq   = (const int*)d_in[1];
    const float* SeqtoBlur = (const float*)d_in[2];
    const float* BlurMat   = (const float*)d_in[3];
    const int*   avged_len = (const int*)d_in[4];
    float* out = (float*)d_out;

    // 1) matmul + ramps first: reads BlurMat/seq while L3 is still warm from
    //    the harness's input restore (the big memcpy below would evict them).
    blur_matmul_ramps<<<NMAT + NRMP, 256, 0, stream>>>(seq, len_seq, BlurMat,
                                                       avged_len, out);

    // 2) SeqtoBlur passthrough via the runtime's tuned d2d copy
    //    (graph-capture-legal per G9; same kernel family as the 6.6 TB/s fill).
    hipMemcpyAsync(out + OFF_S2B, SeqtoBlur,
                   (size_t)BB * TT * TT * sizeof(float),
                   hipMemcpyDeviceToDevice, stream);
}

// Round 13
// 344.861 us; speedup vs baseline: 1.0278x; 1.0278x over previous
//
#include <hip/hip_runtime.h>
#include <hip/hip_bf16.h>

// Problem constants
#define BB 128
#define TT 512
#define DD 128
#define CAP 64            // per-column nonzero list capacity (overflow -> dense fallback)

// Native vector type for nontemporal builtins (HIP_vector_type is rejected).
typedef float f4 __attribute__((ext_vector_type(4)));

// Output layout (flat float32, concatenated in reference return order)
static const size_t OFF_S2B  = 0;                       // SeqtoBlur  [B,T,T]
static const size_t OFF_AVG  = (size_t)BB * TT * TT;    // avged_seq  [B,T,D]
static const size_t OFF_R    = OFF_AVG + (size_t)BB * TT * DD;  // R [B,T]
static const size_t OFF_AR   = OFF_R + (size_t)BB * TT;         // avged_R [B,T]
static const size_t OFF_LEN  = OFF_AR + (size_t)BB * TT;        // avged_len [B]

// ---------------------------------------------------------------------------
// Measured-best configuration (R8): single fused kernel, 5-way interleaved
// roles (grid = 10240):
//   blk % 5 == 4  -> matmul block q = blk/5          (2048 blocks)
//   else          -> copy block  cb = q*4 + (blk%5)  (8192 blocks)
//
// Session ledger: every structural variant (1:1 interleave, matmul-first
// ordering, deep-ILP copy waves, runtime hipMemcpyAsync) lands at kernel-
// portion 100-109 us for ~386 MB effective movement (~3.9 TB/s) — within
// ~10% of the 4.25 TB/s mixed-stream rate the ROCm runtime's own restore
// copies achieve in the same capture. This config was the best (345 us).
//
// Matmul sparsity structure (verified against every reference branch):
//   * Tc = len_seq[b] <= 2 -> BlurMat == I -> avged_seq[b] = seq[b]
//   * all nonzeros have col < avged_len[b] -> chunks beyond: write zeros
//   * nonzeros in column i have row in [i, Tc) -> read row-groups [i0, Tc)
// ---------------------------------------------------------------------------
__global__ __launch_bounds__(256) void blur_fused(
        const float* __restrict__ seq,        // [B,T,D]
        const int*   __restrict__ len_seq,    // [B]
        const float* __restrict__ SeqtoBlur,  // [B,T,T]
        const float* __restrict__ BlurMat,    // [B,T,T]
        const int*   __restrict__ avged_len,  // [B]
        float* __restrict__ out) {

    __shared__ int   cnt[32];
    __shared__ int   tlist[32][CAP];
    __shared__ float wlist[32][CAP];

    int blk = blockIdx.x;
    int tid = threadIdx.x;
    int q = blk / 5;
    int r = blk - q * 5;

    if (r == 4) {
        // ===== Role A: avged_seq[b,i,d] = sum_t BlurMat[b,t,i]*seq[b,t,d] =====
        int b  = q >> 4;             // 16 column-chunks per batch
        int i0 = (q & 15) * 32;
        int Tc = len_seq[b];
        int navl = avged_len[b];

        int il = tid & 31;           // owned column within chunk
        int dbase = (tid >> 5) * 16; // owned d-range

        if (Tc <= 2) {
            // BlurMat == I_512: avged_seq[b] = seq[b]. Pure 16B-per-lane copy.
            const f4* srow = (const f4*)(seq + ((size_t)b * TT + i0 + il) * DD + dbase);
            f4* drow = (f4*)(out + OFF_AVG + ((size_t)b * TT + i0 + il) * DD + dbase);
            #pragma unroll
            for (int k = 0; k < 4; ++k)
                __builtin_nontemporal_store(__builtin_nontemporal_load(srow + k), drow + k);
            return;   // block-uniform exit
        }

        if (i0 >= navl) {
            // Column-cut: every column in this chunk is all-zero -> write zeros.
            f4 z = {0.f, 0.f, 0.f, 0.f};
            f4* drow = (f4*)(out + OFF_AVG + ((size_t)b * TT + i0 + il) * DD + dbase);
            #pragma unroll
            for (int k = 0; k < 4; ++k) __builtin_nontemporal_store(z, drow + k);
            return;   // block-uniform exit (navl is uniform across the block)
        }

        if (tid < 32) cnt[tid] = 0;
        __syncthreads();

        const float* Ab = BlurMat + (size_t)b * TT * TT;
        int ci = (tid & 7) * 4;
        int t0 = tid >> 3;                 // 0..31
        int g0   = i0 >> 7;                // first row-group that can hold a nonzero
        int gend = (Tc + 127) >> 7;        // 1..4, block-uniform

        // Phase 1a: issue all loads before any compaction (deep MLP).
        f4 v[16];
        #pragma unroll
        for (int g = 0; g < 4; ++g) {
            if (g >= g0 && g < gend) {
                #pragma unroll
                for (int qq = 0; qq < 4; ++qq) {
                    int t = t0 + g * 128 + qq * 32;
                    v[g * 4 + qq] = __builtin_nontemporal_load(
                        (const f4*)(Ab + (size_t)t * TT + i0 + ci));
                }
            }
        }

        // Phase 1b: compact nonzeros into per-column LDS lists.
        #pragma unroll
        for (int g = 0; g < 4; ++g) {
            if (g >= g0 && g < gend) {
                #pragma unroll
                for (int qq = 0; qq < 4; ++qq) {
                    int t = t0 + g * 128 + qq * 32;
                    f4 w4 = v[g * 4 + qq];
                    if (w4.x != 0.f) { int s = atomicAdd(&cnt[ci+0], 1); if (s < CAP) { tlist[ci+0][s] = t; wlist[ci+0][s] = w4.x; } }
                    if (w4.y != 0.f) { int s = atomicAdd(&cnt[ci+1], 1); if (s < CAP) { tlist[ci+1][s] = t; wlist[ci+1][s] = w4.y; } }
                    if (w4.z != 0.f) { int s = atomicAdd(&cnt[ci+2], 1); if (s < CAP) { tlist[ci+2][s] = t; wlist[ci+2][s] = w4.z; } }
                    if (w4.w != 0.f) { int s = atomicAdd(&cnt[ci+3], 1); if (s < CAP) { tlist[ci+3][s] = t; wlist[ci+3][s] = w4.w; } }
                }
            }
        }
        __syncthreads();

        // Phase 2: apply the (few) nonzeros of the owned column.
        float acc[16];
        #pragma unroll
        for (int k = 0; k < 16; ++k) acc[k] = 0.f;

        const float* Sb = seq + (size_t)b * TT * DD + dbase;
        int n = cnt[il];

        if (n <= CAP) {
            for (int j = 0; j < n; ++j) {
                int   t = tlist[il][j];
                float w = wlist[il][j];
                const float* srow = Sb + (size_t)t * DD;
                #pragma unroll
                for (int k = 0; k < 4; ++k) {
                    float4 s = *(const float4*)(srow + k * 4);
                    acc[k*4+0] += w * s.x;
                    acc[k*4+1] += w * s.y;
                    acc[k*4+2] += w * s.z;
                    acc[k*4+3] += w * s.w;
                }
            }
        } else {
            // Dense fallback (list overflow) — data-dependent safety net.
            for (int t = i0; t < Tc; ++t) {
                float w = Ab[(size_t)t * TT + i0 + il];
                if (w != 0.f) {
                    const float* srow = Sb + (size_t)t * DD;
                    #pragma unroll
                    for (int k = 0; k < 4; ++k) {
                        float4 s = *(const float4*)(srow + k * 4);
                        acc[k*4+0] += w * s.x;
                        acc[k*4+1] += w * s.y;
                        acc[k*4+2] += w * s.z;
                        acc[k*4+3] += w * s.w;
                    }
                }
            }
        }

        float* Cb = out + OFF_AVG + (size_t)b * TT * DD + (size_t)(i0 + il) * DD + dbase;
        #pragma unroll
        for (int k = 0; k < 4; ++k) {
            *(float4*)(Cb + k * 4) = make_float4(acc[k*4], acc[k*4+1], acc[k*4+2], acc[k*4+3]);
        }
    } else {
        // ===== Role B: SeqtoBlur copy (+ ramps on first 256 copy blocks) =====
        int cb = q * 4 + r;    // 0..8191

        if (cb < 256) {
            // Ramps + avged_len cast: one elem per thread, idx in [0, B*T)
            int idx = cb * 256 + tid;
            int b = idx >> 9;          // /T
            int t = idx & (TT - 1);
            float l1 = (float)len_seq[b];
            float l2 = (float)avged_len[b];
            float p = (float)t;
            out[OFF_R  + idx] = (p < l1) ? (p + 1.f) / fmaxf(l1, 1.f) : 0.f;
            out[OFF_AR + idx] = (p < l2) ? (p + 1.f) / fmaxf(l2, 1.f) : 0.f;
            if (t == 0) out[OFF_LEN + b] = l2;
        }

        // Straight-line copy: 8192 blocks x 256 thr x 4 f4 == 8388608 exactly.
        const f4* src = (const f4*)SeqtoBlur;
        f4* dst = (f4*)(out + OFF_S2B);
        int i = cb * 1024 + tid;
        f4 a0 = __builtin_nontemporal_load(src + i);
        f4 a1 = __builtin_nontemporal_load(src + i + 256);
        f4 a2 = __builtin_nontemporal_load(src + i + 512);
        f4 a3 = __builtin_nontemporal_load(src + i + 768);
        __builtin_nontemporal_store(a0, dst + i);
        __builtin_nontemporal_store(a1, dst + i + 256);
        __builtin_nontemporal_store(a2, dst + i + 512);
        __builtin_nontemporal_store(a3, dst + i + 768);
    }
}

extern "C" void kernel_launch(void* const* d_in, const int* in_sizes, int n_in,
                              void* d_out, int out_size, void* d_ws, size_t ws_size,
                              hipStream_t stream) {
    const float* seq       = (const float*)d_in[0];
    const int*   len_seq   = (const int*)d_in[1];
    const float* SeqtoBlur = (const float*)d_in[2];
    const float* BlurMat   = (const float*)d_in[3];
    const int*   avged_len = (const int*)d_in[4];
    float* out = (float*)d_out;

    blur_fused<<<10240, 256, 0, stream>>>(seq, len_seq, SeqtoBlur, BlurMat,
                                          avged_len, out);
}